// Round 12
// baseline (54.730 us; speedup 1.0000x reference)
//
#include <hip/hip_runtime.h>
#include <hip/hip_bf16.h>

#define NPTS  262144
#define CIN   16
#define COUT  32
#define NTAPS 27
#define BLK   512

typedef __attribute__((ext_vector_type(8)))  short short8v;   // 8 bf16 (4 VGPRs)
typedef __attribute__((ext_vector_type(16))) float f32x16;    // MFMA accumulator
typedef __attribute__((ext_vector_type(4)))  int   int4v;     // for nontemporal ld

// One kernel, no workspace. Per wave: 32 points x 32 cout via 27x
// v_mfma_f32_32x32x16_bf16. Symmetric A/B fragment packing (cin =
// (lane>>5)*8 + e on both sides) so the HW k-permutation cancels — verified
// rounds 2-10. Gathers read fp32 feature rows (64 B = exactly one cache
// line, 100% utilization) and convert to bf16 in-register; nbr/out use
// nontemporal accesses to keep L2/L3 for the feature table.
__global__ __launch_bounds__(BLK, 4) void sct_mfma_kernel(
    const float* __restrict__ feat,            // [N,16] fp32
    const float* __restrict__ Wg,              // [27,16,32] fp32
    const float* __restrict__ bias,            // [32]
    const int*   __restrict__ nbr,             // [N,27]
    float*       __restrict__ out)             // [N,32]
{
    __shared__ short bpack[NTAPS * 512];       // 27648 B, one copy per 8 waves

    const int tid = threadIdx.x;
    // Coalesced W staging: 3456 float4 total; thread i takes f = tid + 512*q.
    // f -> (tap = f>>7, cin = (f&127)>>3, cout quad = f&7); write 4 bf16 to
    // bpack[(tap<<9) + ((cin>>3)<<8) + cout*8 + (cin&7)].
    #pragma unroll
    for (int q = 0; q < 7; ++q) {
        const int f = tid + q * BLK;
        if (f < 3456) {
            const float4 w4 = ((const float4*)Wg)[f];
            const int tap = f >> 7;
            const int r   = f & 127;
            const int cin = r >> 3;
            const int c0  = (r & 7) * 4;
            const int base = (tap << 9) + ((cin >> 3) << 8) + (cin & 7);
            const __hip_bfloat16 h0 = __float2bfloat16(w4.x);
            const __hip_bfloat16 h1 = __float2bfloat16(w4.y);
            const __hip_bfloat16 h2 = __float2bfloat16(w4.z);
            const __hip_bfloat16 h3 = __float2bfloat16(w4.w);
            bpack[base + (c0 + 0) * 8] = *(const short*)&h0;
            bpack[base + (c0 + 1) * 8] = *(const short*)&h1;
            bpack[base + (c0 + 2) * 8] = *(const short*)&h2;
            bpack[base + (c0 + 3) * 8] = *(const short*)&h3;
        }
    }
    __syncthreads();

    const int lane = tid & 63;
    const int wv   = tid >> 6;                        // 0..7
    const int p0   = blockIdx.x * 256 + wv * 32;      // this wave's 32 points
    const int prow = lane & 31;                       // A-row (point) / B-col (cout)
    const int g    = lane >> 5;                       // k-group
    const int* nb  = nbr + (long)(p0 + prow) * NTAPS;

    f32x16 acc;
    {
        const float b = bias[prow];
        #pragma unroll
        for (int r2 = 0; r2 < 16; ++r2) acc[r2] = b;
    }

    auto tap1 = [&](int t, int id) {
        short8v a = {};
        if (id >= 0) {                                 // exec-masked (~12.5% valid)
            const float4* fp = (const float4*)(feat + (long)id * CIN + g * 8);
            const float4 x = fp[0];
            const float4 y = fp[1];
            union { short8v v; __hip_bfloat162 h[4]; } u;
            u.h[0] = __float22bfloat162_rn(float2{x.x, x.y});
            u.h[1] = __float22bfloat162_rn(float2{x.z, x.w});
            u.h[2] = __float22bfloat162_rn(float2{y.x, y.y});
            u.h[3] = __float22bfloat162_rn(float2{y.z, y.w});
            a = u.v;
        }
        const short8v bf = *(const short8v*)&bpack[(t << 9) + (lane << 3)];
        acc = __builtin_amdgcn_mfma_f32_32x32x16_bf16(a, bf, acc, 0, 0, 0);
    };

    // 6 groups of 4 taps + tail of 3; nbr via nontemporal int4 (read-once)
    #pragma unroll
    for (int grp = 0; grp < 6; ++grp) {
        const int4v v = __builtin_nontemporal_load((const int4v*)(nb + 4 * grp));
        tap1(4 * grp + 0, v.x);
        tap1(4 * grp + 1, v.y);
        tap1(4 * grp + 2, v.z);
        tap1(4 * grp + 3, v.w);
    }
    {
        const int i24 = __builtin_nontemporal_load(nb + 24);
        const int i25 = __builtin_nontemporal_load(nb + 25);
        const int i26 = __builtin_nontemporal_load(nb + 26);
        tap1(24, i24);
        tap1(25, i25);
        tap1(26, i26);
    }

    // D: col = lane&31 (cout), row = (reg&3) + 8*(reg>>2) + 4*(lane>>5) (point)
    #pragma unroll
    for (int r2 = 0; r2 < 16; ++r2) {
        const int row = (r2 & 3) + 8 * (r2 >> 2) + 4 * g;
        __builtin_nontemporal_store(acc[r2], &out[(long)(p0 + row) * COUT + prow]);
    }
}

extern "C" void kernel_launch(void* const* d_in, const int* in_sizes, int n_in,
                              void* d_out, int out_size, void* d_ws, size_t ws_size,
                              hipStream_t stream) {
    const float* feat = (const float*)d_in[0];
    const float* Wg   = (const float*)d_in[1];
    const float* bias = (const float*)d_in[2];
    const int*   nbr  = (const int*)d_in[3];
    float*       out  = (float*)d_out;

    sct_mfma_kernel<<<NPTS / 256, BLK, 0, stream>>>(feat, Wg, bias, nbr, out);
}